// Round 7
// baseline (296.299 us; speedup 1.0000x reference)
//
#include <hip/hip_runtime.h>
#include <math.h>

#define N 4
#define V 5
#define C 128
#define H 128
#define W 128
#define P 4096
#define HW (H * W)
#define PTS 16               // points per gather block
#define NPV (N * P * V)      // 81920 point-view records

typedef float  fvec4 __attribute__((ext_vector_type(4)));
typedef unsigned short usvec4 __attribute__((ext_vector_type(4)));

__device__ __forceinline__ unsigned short f2bf_rne(float x) {
    unsigned u = __float_as_uint(x);
    unsigned rounding = 0x7fffu + ((u >> 16) & 1u);
    return (unsigned short)((u + rounding) >> 16);
}
__device__ __forceinline__ float bf2f(unsigned short b) {
    return __uint_as_float(((unsigned)b) << 16);
}

// ---------------------------------------------------------------------------
// Pass 1: one thread per (point,view). Computes the projection ONCE, writes
// corner indices + validity-folded weights + bound to workspace, marks the
// touched 16x16 tiles (plain stores of 1u; ws poison 0xAA != 1 => untouched;
// stale/extra marks only cause extra transpose work, never wrong results).
// Also does the sample_points passthrough (NPV == N*P*5 elements).
// ---------------------------------------------------------------------------
__global__ __launch_bounds__(256) void project_kernel(
    const float* __restrict__ sp,      // (N,P,5)
    const float* __restrict__ Rm, const float* __restrict__ Tm,
    const float* __restrict__ fv, const float* __restrict__ cv,
    const float* __restrict__ kv, const float* __restrict__ pv,
    const float* __restrict__ trans, const float* __restrict__ wh,
    const float* __restrict__ fmsz,
    int4*  __restrict__ ws_idx,        // [NPV]
    float4* __restrict__ ws_w,         // [NPV]
    float* __restrict__ ws_bnd,        // [NPV]
    unsigned* __restrict__ flags,      // [N*V*64]
    float* __restrict__ out_sp)        // (N,P,5)
{
    const int tid = blockIdx.x * 256 + threadIdx.x;   // 0..NPV-1 exactly
    out_sp[tid] = sp[tid];                            // NPV == N*P*5

    const int pt = tid / V;            // global point 0..N*P-1
    const int v  = tid - pt * V;
    const int n  = pt >> 12;           // P = 4096
    const int nv = n * V + v;

    const float X = sp[pt * 5 + 0];
    const float Y = sp[pt * 5 + 1];
    const float Z = sp[pt * 5 + 2];

    const float* Rv = Rm + nv * 9;
    const float tx = Tm[nv * 3 + 0], ty = Tm[nv * 3 + 1], tz = Tm[nv * 3 + 2];
    const float px = X - tx, py = Y - ty, pz = Z - tz;
    const float Xc0 = Rv[0] * px + Rv[1] * py + Rv[2] * pz;
    const float Xc1 = Rv[3] * px + Rv[4] * py + Rv[5] * pz;
    const float Xc2 = Rv[6] * px + Rv[7] * py + Rv[8] * pz;
    const float xn = Xc0 / Xc2;
    const float yn = Xc1 / Xc2;
    const float r2 = xn * xn + yn * yn;
    const float k1 = kv[nv * 3 + 0], k2 = kv[nv * 3 + 1], k3 = kv[nv * 3 + 2];
    const float p1 = pv[nv * 2 + 0], p2 = pv[nv * 2 + 1];
    const float radial = 1.0f + k1 * r2 + k2 * r2 * r2 + k3 * r2 * r2 * r2;
    const float xd = xn * radial + 2.0f * p1 * xn * yn + p2 * (r2 + 2.0f * xn * xn);
    const float yd = yn * radial + p1 * (r2 + 2.0f * yn * yn) + 2.0f * p2 * xn * yn;
    const float xy0 = xd * fv[nv * 2 + 0] + cv[nv * 2 + 0];
    const float xy1 = yd * fv[nv * 2 + 1] + cv[nv * 2 + 1];
    const float width  = wh[nv * 2 + 0];
    const float height = wh[nv * 2 + 1];
    const bool bound = (xy0 >= 0.0f) && (xy1 >= 0.0f) && (xy0 < width) && (xy1 < height);
    const float maxwh = fmaxf(width, height);
    const float pix0 = fminf(fmaxf(xy0, -1.0f), maxwh);
    const float pix1 = fminf(fmaxf(xy1, -1.0f), maxwh);
    const float* tr = trans + nv * 6;
    const float pt0 = tr[0] * pix0 + tr[1] * pix1 + tr[2];
    const float pt1 = tr[3] * pix0 + tr[4] * pix1 + tr[5];
    const float fm0 = fmsz[0], fm1 = fmsz[1];
    float g0 = pt0 / (fm0 - 1.0f) * 2.0f - 1.0f;
    float g1 = pt1 / (fm1 - 1.0f) * 2.0f - 1.0f;
    g0 = fminf(fmaxf(g0, -1.1f), 1.1f);
    g1 = fminf(fmaxf(g1, -1.1f), 1.1f);

    const float xg = (g0 + 1.0f) * 0.5f * (float)(W - 1);
    const float yg = (g1 + 1.0f) * 0.5f * (float)(H - 1);
    const float x0f = floorf(xg), y0f = floorf(yg);
    const float wx1 = xg - x0f, wx0 = 1.0f - wx1;
    const float wy1 = yg - y0f, wy0 = 1.0f - wy1;
    const int x0 = (int)x0f, y0 = (int)y0f;
    const int x1 = x0 + 1,  y1 = y0 + 1;
    const bool vx0 = (x0 >= 0) && (x0 <= W - 1);
    const bool vx1 = (x1 >= 0) && (x1 <= W - 1);
    const bool vy0 = (y0 >= 0) && (y0 <= H - 1);
    const bool vy1 = (y1 >= 0) && (y1 <= H - 1);
    const int x0c = min(max(x0, 0), W - 1);
    const int x1c = min(max(x1, 0), W - 1);
    const int y0c = min(max(y0, 0), H - 1);
    const int y1c = min(max(y1, 0), H - 1);

    int4 id;
    id.x = y0c * W + x0c;
    id.y = y0c * W + x1c;
    id.z = y1c * W + x0c;
    id.w = y1c * W + x1c;
    ws_idx[tid] = id;

    float4 w;
    w.x = (vx0 && vy0) ? (wx0 * wy0) : 0.0f;
    w.y = (vx1 && vy0) ? (wx1 * wy0) : 0.0f;
    w.z = (vx0 && vy1) ? (wx0 * wy1) : 0.0f;
    w.w = (vx1 && vy1) ? (wx1 * wy1) : 0.0f;
    ws_w[tid] = w;
    ws_bnd[tid] = bound ? 1.0f : 0.0f;

    // mark touched 16x16 tiles (8x8 tile grid per map)
    unsigned* fl = flags + nv * 64;
    const int tx0 = x0c >> 4, tx1 = x1c >> 4;
    const int ty0 = y0c >> 4, ty1 = y1c >> 4;
    fl[ty0 * 8 + tx0] = 1u;
    fl[ty0 * 8 + tx1] = 1u;
    fl[ty1 * 8 + tx0] = 1u;
    fl[ty1 * 8 + tx1] = 1u;
}

// ---------------------------------------------------------------------------
// Pass 2: transpose ONLY touched 16x16 tiles f32 (C,H,W) -> bf16 (H,W,C).
// Block = 256 threads per (tile, nv); untouched tiles exit immediately.
// 4 channel-groups of 32; LDS [256 px][33] (pad keeps stores conflict-free).
// ---------------------------------------------------------------------------
__global__ __launch_bounds__(256) void transpose_tiles_kernel(
    const float* __restrict__ fm, unsigned short* __restrict__ fmT,
    const unsigned* __restrict__ flags)
{
    const int nv   = blockIdx.y;
    const int tile = blockIdx.x;                 // 0..63
    if (flags[nv * 64 + tile] != 1u) return;
    const int ybase = (tile >> 3) * 16;
    const int xbase = (tile & 7) * 16;

    __shared__ float lds[256][33];
    const int t = threadIdx.x;
    const float* src = fm + (size_t)nv * C * HW;
    unsigned short* dst = fmT + (size_t)nv * HW * C;

    for (int cg = 0; cg < 4; ++cg) {
        if (cg) __syncthreads();
        // load 32ch x 256px; lanes = consecutive px -> 64 B row segments
        for (int e = t; e < 8192; e += 256) {
            const int c  = e >> 8;               // 0..31
            const int pxl = e & 255;
            const int y = ybase + (pxl >> 4), x = xbase + (pxl & 15);
            lds[pxl][c] = src[(size_t)(cg * 32 + c) * HW + y * W + x];
        }
        __syncthreads();
        // store: 8 lanes cover one pixel's 32 ch (4 each) -> 64 B segments
        const int c4 = (t & 7) * 4;
        for (int pxl = t >> 3; pxl < 256; pxl += 32) {
            const int y = ybase + (pxl >> 4), x = xbase + (pxl & 15);
            usvec4 o;
            o.x = f2bf_rne(lds[pxl][c4 + 0]);
            o.y = f2bf_rne(lds[pxl][c4 + 1]);
            o.z = f2bf_rne(lds[pxl][c4 + 2]);
            o.w = f2bf_rne(lds[pxl][c4 + 3]);
            *(usvec4*)(dst + (size_t)(y * W + x) * C + cg * 32 + c4) = o;
        }
    }
}

// ---------------------------------------------------------------------------
// Pass 3: gather from bf16 channel-last maps using precomputed records.
// Block = 256 threads, PTS points. 32 threads per point-view, 4 ch/thread.
// ---------------------------------------------------------------------------
__global__ __launch_bounds__(256) void gather_kernel(
    const unsigned short* __restrict__ fmT, // (N,V,H,W,C) bf16
    const int4*  __restrict__ ws_idx,
    const float4* __restrict__ ws_w,
    const float* __restrict__ ws_bnd,
    float* __restrict__ out_feats,     // (N,P,V,C)
    float* __restrict__ out_bound)     // (N,P)
{
    const int pb = blockIdx.x;               // 0 .. N*(P/PTS)-1
    const int n  = pb >> 8;                  // P/PTS = 256
    const int p0 = (pb & 255) * PTS;
    const int t  = threadIdx.x;
    const int base_pt = n * P + p0;
    const int rec0 = base_pt * V;

    __shared__ int   s_idx[PTS * V][4];
    __shared__ float s_w[PTS * V][4];
    __shared__ float s_bnd[PTS * V];
    __shared__ int   s_nan[PTS];

    if (t < PTS) s_nan[t] = 0;
    if (t < PTS * V) {
        const int4  id = ws_idx[rec0 + t];
        const float4 w = ws_w[rec0 + t];
        s_idx[t][0] = id.x; s_idx[t][1] = id.y;
        s_idx[t][2] = id.z; s_idx[t][3] = id.w;
        s_w[t][0] = w.x; s_w[t][1] = w.y; s_w[t][2] = w.z; s_w[t][3] = w.w;
        s_bnd[t] = ws_bnd[rec0 + t];
    }
    __syncthreads();

    {
        const int grp = t >> 5;          // 0..7 point-view group
        const int c4  = (t & 31) * 4;    // channel base
        const unsigned short* img_n = fmT + (size_t)(n * V) * HW * C;
        #pragma unroll 2
        for (int i = grp; i < PTS * V; i += 8) {
            const int pt = i / V;
            const int v  = i - pt * V;
            const unsigned short* img = img_n + (size_t)v * HW * C + c4;
            const usvec4 b00 = *(const usvec4*)(img + (size_t)s_idx[i][0] * C);
            const usvec4 b10 = *(const usvec4*)(img + (size_t)s_idx[i][1] * C);
            const usvec4 b01 = *(const usvec4*)(img + (size_t)s_idx[i][2] * C);
            const usvec4 b11 = *(const usvec4*)(img + (size_t)s_idx[i][3] * C);
            const float w00 = s_w[i][0], w10 = s_w[i][1];
            const float w01 = s_w[i][2], w11 = s_w[i][3];
            const float bnd = s_bnd[i];
            fvec4 f;
            f.x = (bf2f(b00.x) * w00 + bf2f(b10.x) * w10
                 + bf2f(b01.x) * w01 + bf2f(b11.x) * w11) * bnd;
            f.y = (bf2f(b00.y) * w00 + bf2f(b10.y) * w10
                 + bf2f(b01.y) * w01 + bf2f(b11.y) * w11) * bnd;
            f.z = (bf2f(b00.z) * w00 + bf2f(b10.z) * w10
                 + bf2f(b01.z) * w01 + bf2f(b11.z) * w11) * bnd;
            f.w = (bf2f(b00.w) * w00 + bf2f(b10.w) * w10
                 + bf2f(b01.w) * w01 + bf2f(b11.w) * w11) * bnd;
            if ((f.x != f.x) | (f.y != f.y) | (f.z != f.z) | (f.w != f.w))
                s_nan[pt] = 1;           // benign race
            __builtin_nontemporal_store(
                f, (fvec4*)&out_feats[((size_t)(base_pt + pt) * V + v) * C + c4]);
        }
    }
    __syncthreads();

    if (t < PTS) {
        bool any_b = false;
        #pragma unroll
        for (int v = 0; v < V; ++v) any_b |= (s_bnd[t * V + v] != 0.0f);
        out_bound[base_pt + t] = (any_b && (s_nan[t] == 0)) ? 1.0f : 0.0f;
    }
}

extern "C" void kernel_launch(void* const* d_in, const int* in_sizes, int n_in,
                              void* d_out, int out_size, void* d_ws, size_t ws_size,
                              hipStream_t stream) {
    const float* fm    = (const float*)d_in[0];
    const float* sp    = (const float*)d_in[1];
    const float* Rm    = (const float*)d_in[2];
    const float* Tm    = (const float*)d_in[3];
    const float* fv    = (const float*)d_in[4];
    const float* cv    = (const float*)d_in[5];
    const float* kv    = (const float*)d_in[6];
    const float* pv    = (const float*)d_in[7];
    const float* trans = (const float*)d_in[8];
    const float* wh    = (const float*)d_in[9];
    const float* fmsz  = (const float*)d_in[10];

    float* out        = (float*)d_out;
    float* out_feats  = out;
    float* out_bound  = out + (size_t)N * P * V * C;
    float* out_sp     = out_bound + (size_t)N * P;

    // workspace layout
    char* ws = (char*)d_ws;
    unsigned short* fmT = (unsigned short*)ws;                 // 83,886,080 B
    size_t off = (size_t)N * V * HW * C * sizeof(unsigned short);
    int4*   ws_idx = (int4*)(ws + off);   off += (size_t)NPV * sizeof(int4);
    float4* ws_w   = (float4*)(ws + off); off += (size_t)NPV * sizeof(float4);
    float*  ws_bnd = (float*)(ws + off);  off += (size_t)NPV * sizeof(float);
    unsigned* flags = (unsigned*)(ws + off);                   // N*V*64 u32

    project_kernel<<<NPV / 256, 256, 0, stream>>>(
        sp, Rm, Tm, fv, cv, kv, pv, trans, wh, fmsz,
        ws_idx, ws_w, ws_bnd, flags, out_sp);

    dim3 tgrid(64, N * V);
    transpose_tiles_kernel<<<tgrid, 256, 0, stream>>>(fm, fmT, flags);

    gather_kernel<<<N * (P / PTS), 256, 0, stream>>>(
        fmT, ws_idx, ws_w, ws_bnd, out_feats, out_bound);
}

// Round 8
// 290.511 us; speedup vs baseline: 1.0199x; 1.0199x over previous
//
#include <hip/hip_runtime.h>
#include <math.h>

#define N 4
#define V 5
#define C 128
#define H 128
#define W 128
#define P 4096
#define HW (H * W)
#define PPB 32               // points per gather block
#define NPV (N * P * V)

typedef float  fvec4 __attribute__((ext_vector_type(4)));
typedef unsigned short usvec4 __attribute__((ext_vector_type(4)));

__device__ __forceinline__ unsigned short f2bf_rne(float x) {
    unsigned u = __float_as_uint(x);
    unsigned rounding = 0x7fffu + ((u >> 16) & 1u);
    return (unsigned short)((u + rounding) >> 16);
}
__device__ __forceinline__ float bf2f(unsigned short b) {
    return __uint_as_float(((unsigned)b) << 16);
}

// ---------------------------------------------------------------------------
// Dense transpose (N,V,C,H,W) f32 -> (N,V,H,W,C) bf16 (round-6 version:
// fully-coalesced fvec4 loads, usvec4 stores, conflict-free LDS tile).
// ---------------------------------------------------------------------------
__global__ __launch_bounds__(256) void transpose_kernel(
    const float* __restrict__ fm, unsigned short* __restrict__ fmT)
{
    const int nv  = blockIdx.y;
    const int hw0 = blockIdx.x * 64;
    __shared__ float lds[64][C + 1];

    const int t = threadIdx.x;
    {
        const int hwl = (t & 15) * 4;
        const int cb  = t >> 4;
        const float* src = fm + (size_t)nv * C * HW + hw0 + hwl;
        for (int c = cb; c < C; c += 16) {
            const fvec4 v = __builtin_nontemporal_load(
                (const fvec4*)(src + (size_t)c * HW));
            lds[hwl + 0][c] = v.x;
            lds[hwl + 1][c] = v.y;
            lds[hwl + 2][c] = v.z;
            lds[hwl + 3][c] = v.w;
        }
    }
    __syncthreads();
    {
        const int c4 = (t & 31) * 4;
        unsigned short* dst = fmT + ((size_t)nv * HW + hw0) * C + c4;
        for (int hw = (t >> 5); hw < 64; hw += 8) {
            const fvec4 v = *(const fvec4*)&lds[hw][c4];
            usvec4 o;
            o.x = f2bf_rne(v.x);
            o.y = f2bf_rne(v.y);
            o.z = f2bf_rne(v.z);
            o.w = f2bf_rne(v.w);
            *(usvec4*)(dst + (size_t)hw * C) = o;
        }
    }
}

// ---------------------------------------------------------------------------
// Projection: one thread per point; computes all V views, writes records
// in (nv, p) layout (bound folded into weights), bounding, and the
// sample_points passthrough. NaN path: finite inputs (weights in [0,1],
// values finite) cannot produce NaN, so bounding = OR_v(bound).
// ---------------------------------------------------------------------------
__global__ __launch_bounds__(256) void project_kernel(
    const float* __restrict__ sp,
    const float* __restrict__ Rm, const float* __restrict__ Tm,
    const float* __restrict__ fv, const float* __restrict__ cv,
    const float* __restrict__ kv, const float* __restrict__ pv,
    const float* __restrict__ trans, const float* __restrict__ wh,
    const float* __restrict__ fmsz,
    int4*   __restrict__ ws_idx,       // [N*V*P] in (nv, p) order
    float4* __restrict__ ws_w,         // [N*V*P]
    float*  __restrict__ out_bound,    // (N,P)
    float*  __restrict__ out_sp)       // (N,P,5)
{
    const int pt = blockIdx.x * 256 + threadIdx.x;   // 0..N*P-1
    const int n  = pt >> 12;                         // P = 4096
    const int p  = pt & 4095;

    const float s0 = sp[pt * 5 + 0];
    const float s1 = sp[pt * 5 + 1];
    const float s2 = sp[pt * 5 + 2];
    const float s3 = sp[pt * 5 + 3];
    const float s4 = sp[pt * 5 + 4];
    out_sp[pt * 5 + 0] = s0;
    out_sp[pt * 5 + 1] = s1;
    out_sp[pt * 5 + 2] = s2;
    out_sp[pt * 5 + 3] = s3;
    out_sp[pt * 5 + 4] = s4;

    const float fm0 = fmsz[0], fm1 = fmsz[1];
    bool any_b = false;

    #pragma unroll
    for (int v = 0; v < V; ++v) {
        const int nv = n * V + v;
        const float* Rv = Rm + nv * 9;
        const float tx = Tm[nv * 3 + 0], ty = Tm[nv * 3 + 1], tz = Tm[nv * 3 + 2];
        const float px = s0 - tx, py = s1 - ty, pz = s2 - tz;
        const float Xc0 = Rv[0] * px + Rv[1] * py + Rv[2] * pz;
        const float Xc1 = Rv[3] * px + Rv[4] * py + Rv[5] * pz;
        const float Xc2 = Rv[6] * px + Rv[7] * py + Rv[8] * pz;
        const float xn = Xc0 / Xc2;
        const float yn = Xc1 / Xc2;
        const float r2 = xn * xn + yn * yn;
        const float k1 = kv[nv * 3 + 0], k2 = kv[nv * 3 + 1], k3 = kv[nv * 3 + 2];
        const float p1 = pv[nv * 2 + 0], p2 = pv[nv * 2 + 1];
        const float radial = 1.0f + k1 * r2 + k2 * r2 * r2 + k3 * r2 * r2 * r2;
        const float xd = xn * radial + 2.0f * p1 * xn * yn + p2 * (r2 + 2.0f * xn * xn);
        const float yd = yn * radial + p1 * (r2 + 2.0f * yn * yn) + 2.0f * p2 * xn * yn;
        const float xy0 = xd * fv[nv * 2 + 0] + cv[nv * 2 + 0];
        const float xy1 = yd * fv[nv * 2 + 1] + cv[nv * 2 + 1];
        const float width  = wh[nv * 2 + 0];
        const float height = wh[nv * 2 + 1];
        const bool bound = (xy0 >= 0.0f) && (xy1 >= 0.0f) && (xy0 < width) && (xy1 < height);
        const float maxwh = fmaxf(width, height);
        const float pix0 = fminf(fmaxf(xy0, -1.0f), maxwh);
        const float pix1 = fminf(fmaxf(xy1, -1.0f), maxwh);
        const float* tr = trans + nv * 6;
        const float pt0 = tr[0] * pix0 + tr[1] * pix1 + tr[2];
        const float pt1 = tr[3] * pix0 + tr[4] * pix1 + tr[5];
        float g0 = pt0 / (fm0 - 1.0f) * 2.0f - 1.0f;
        float g1 = pt1 / (fm1 - 1.0f) * 2.0f - 1.0f;
        g0 = fminf(fmaxf(g0, -1.1f), 1.1f);
        g1 = fminf(fmaxf(g1, -1.1f), 1.1f);

        const float xg = (g0 + 1.0f) * 0.5f * (float)(W - 1);
        const float yg = (g1 + 1.0f) * 0.5f * (float)(H - 1);
        const float x0f = floorf(xg), y0f = floorf(yg);
        const float wx1 = xg - x0f, wx0 = 1.0f - wx1;
        const float wy1 = yg - y0f, wy0 = 1.0f - wy1;
        const int x0 = (int)x0f, y0 = (int)y0f;
        const int x1 = x0 + 1,  y1 = y0 + 1;
        const bool vx0 = (x0 >= 0) && (x0 <= W - 1);
        const bool vx1 = (x1 >= 0) && (x1 <= W - 1);
        const bool vy0 = (y0 >= 0) && (y0 <= H - 1);
        const bool vy1 = (y1 >= 0) && (y1 <= H - 1);
        const int x0c = min(max(x0, 0), W - 1);
        const int x1c = min(max(x1, 0), W - 1);
        const int y0c = min(max(y0, 0), H - 1);
        const int y1c = min(max(y1, 0), H - 1);

        const float bnd = bound ? 1.0f : 0.0f;
        int4 id;
        id.x = y0c * W + x0c;
        id.y = y0c * W + x1c;
        id.z = y1c * W + x0c;
        id.w = y1c * W + x1c;
        float4 w;
        w.x = ((vx0 && vy0) ? (wx0 * wy0) : 0.0f) * bnd;
        w.y = ((vx1 && vy0) ? (wx1 * wy0) : 0.0f) * bnd;
        w.z = ((vx0 && vy1) ? (wx0 * wy1) : 0.0f) * bnd;
        w.w = ((vx1 && vy1) ? (wx1 * wy1) : 0.0f) * bnd;

        const int rec = nv * P + p;
        ws_idx[rec] = id;
        ws_w[rec]   = w;
        any_b |= bound;
    }

    out_bound[pt] = any_b ? 1.0f : 0.0f;
}

// ---------------------------------------------------------------------------
// Gather: one block per (nv, 32-point chunk), nv-major dispatch so blocks
// sharing a view-map are temporally clustered -> hot region (~1 MB) lives
// in per-XCD L2. 256 threads: 8 groups x 32 lanes, 4 channels/lane,
// 4 fully-unrolled point-views per group (16 corner loads in flight).
// ---------------------------------------------------------------------------
__global__ __launch_bounds__(256) void gather_kernel(
    const unsigned short* __restrict__ fmT, // (N,V,H,W,C) bf16
    const int4*  __restrict__ ws_idx,       // (nv, p)
    const float4* __restrict__ ws_w,        // (nv, p)
    float* __restrict__ out_feats)          // (N,P,V,C)
{
    const int blk   = blockIdx.x;            // nv * (P/PPB) + chunk
    const int nv    = blk >> 7;              // P/PPB = 128
    const int chunk = blk & 127;
    const int n     = nv / V;
    const int v     = nv - n * V;
    const int p0    = chunk * PPB;
    const int t     = threadIdx.x;
    const int rec0  = nv * P + p0;

    __shared__ int4   s_idx[PPB];
    __shared__ float4 s_w[PPB];

    if (t < PPB) {
        s_idx[t] = ws_idx[rec0 + t];
        s_w[t]   = ws_w[rec0 + t];
    }
    __syncthreads();

    const int grp = t >> 5;                  // 0..7
    const int c4  = (t & 31) * 4;
    const unsigned short* img = fmT + (size_t)nv * HW * C + c4;
    const size_t out_base = ((size_t)(n * P + p0) * V + v) * C + c4;

    #pragma unroll
    for (int i = grp; i < PPB; i += 8) {
        const int4   id = s_idx[i];
        const float4 w  = s_w[i];
        const usvec4 b00 = *(const usvec4*)(img + (size_t)id.x * C);
        const usvec4 b10 = *(const usvec4*)(img + (size_t)id.y * C);
        const usvec4 b01 = *(const usvec4*)(img + (size_t)id.z * C);
        const usvec4 b11 = *(const usvec4*)(img + (size_t)id.w * C);
        fvec4 f;
        f.x = bf2f(b00.x) * w.x + bf2f(b10.x) * w.y
            + bf2f(b01.x) * w.z + bf2f(b11.x) * w.w;
        f.y = bf2f(b00.y) * w.x + bf2f(b10.y) * w.y
            + bf2f(b01.y) * w.z + bf2f(b11.y) * w.w;
        f.z = bf2f(b00.z) * w.x + bf2f(b10.z) * w.y
            + bf2f(b01.z) * w.z + bf2f(b11.z) * w.w;
        f.w = bf2f(b00.w) * w.x + bf2f(b10.w) * w.y
            + bf2f(b01.w) * w.z + bf2f(b11.w) * w.w;
        __builtin_nontemporal_store(
            f, (fvec4*)&out_feats[out_base + (size_t)i * V * C]);
    }
}

extern "C" void kernel_launch(void* const* d_in, const int* in_sizes, int n_in,
                              void* d_out, int out_size, void* d_ws, size_t ws_size,
                              hipStream_t stream) {
    const float* fm    = (const float*)d_in[0];
    const float* sp    = (const float*)d_in[1];
    const float* Rm    = (const float*)d_in[2];
    const float* Tm    = (const float*)d_in[3];
    const float* fv    = (const float*)d_in[4];
    const float* cv    = (const float*)d_in[5];
    const float* kv    = (const float*)d_in[6];
    const float* pv    = (const float*)d_in[7];
    const float* trans = (const float*)d_in[8];
    const float* wh    = (const float*)d_in[9];
    const float* fmsz  = (const float*)d_in[10];

    float* out        = (float*)d_out;
    float* out_feats  = out;
    float* out_bound  = out + (size_t)N * P * V * C;
    float* out_sp     = out_bound + (size_t)N * P;

    char* ws = (char*)d_ws;
    unsigned short* fmT = (unsigned short*)ws;                    // 83.9 MB
    size_t off = (size_t)N * V * HW * C * sizeof(unsigned short);
    int4*   ws_idx = (int4*)(ws + off);   off += (size_t)NPV * sizeof(int4);
    float4* ws_w   = (float4*)(ws + off);

    dim3 tgrid(HW / 64, N * V);
    transpose_kernel<<<tgrid, 256, 0, stream>>>(fm, fmT);

    project_kernel<<<(N * P) / 256, 256, 0, stream>>>(
        sp, Rm, Tm, fv, cv, kv, pv, trans, wh, fmsz,
        ws_idx, ws_w, out_bound, out_sp);

    gather_kernel<<<(N * V) * (P / PPB), 256, 0, stream>>>(
        fmT, ws_idx, ws_w, out_feats);
}